// Round 8
// baseline (23657.523 us; speedup 1.0000x reference)
//
#include <hip/hip_runtime.h>

// ============================================================================
// AttnDecoderRNN round 13: R12's column-partition (FETCH 8.2->1.9 GB, proven)
// + 2-phase/2-barrier schedule + no LDS bulk staging.
//  Phase 1 (attention, q2<8, 1 block/batch): q = h[b]·Wa computed IN-PHASE
//    (wave-per-64-cols dot, Wa L2-resident), Eq->LDS, scores, softmax, ctx.
//  Phase 2: C-blocks (q2 in 8..12, 16 h-cols each): gh = h·Whh_cols and
//    gi = ctx·Wih_cols via MFMA with A-frags batch-cloaded from LLC (no LDS
//    stage), 3 chains/wave, GRU with f32 hL persistent; writes h(t) bf16 to
//    DOUBLE-BUFFERED hbf.  L-blocks (q2 12..14): logits(t-1) = h(t-1)·Wout.
//  hbf double-buffer removes the h-write/read race -> only 2 barriers/step.
//  Per-XCD set: Wa 0.5 + keys 2.1 + enc8 1.05 + col-slices 0.33 = 3.97 MB.
//  Zero atomics, single writer per address.  Numerics == R12 (absmax .03125).
// ============================================================================

typedef short s8v __attribute__((ext_vector_type(8)));
typedef float f4v __attribute__((ext_vector_type(4)));
typedef float f2v __attribute__((ext_vector_type(2)));
typedef unsigned long long u64;

// ws byte offsets
#define OFF_BAR    0u          // slots [0..111], release flags at uint 128+16*x
#define OFF_HBF    4096u       // 2 x [64][512] bf16 (double-buffered h)
#define OFF_CTX    135168u     // [64][512] bf16 normalized ctx
#define OFF_WCAT   200704u     // [2560][512] bf16 : Wa | Whh | Wout
#define OFF_WIH    2822144u    // [1536][512] bf16
#define OFF_KEYS   4395008u    // [64*256][512] bf16 : Ek = exp(2*(Ua.enc+bu))
#define OFF_ENC8   21172224u   // [64*256*512] fp8
#define MEMSET_BYTES 135168u   // bar + both hbf buffers (h0 = 0)

// d_out offsets (floats)
#define OUT_HFIN   8388608u
#define OUT_ATTN   8421376u

__device__ __forceinline__ unsigned short f2bf(float f) {
  union { float f; unsigned u; } a; a.f = f;
  unsigned r = a.u + 0x7fffu + ((a.u >> 16) & 1u);
  return (unsigned short)(r >> 16);
}
__device__ __forceinline__ float bf2f(unsigned short h) {
  union { unsigned u; float f; } a; a.u = (unsigned)h << 16; return a.f;
}
__device__ __forceinline__ float cload(const float* p) {
  return __hip_atomic_load(p, __ATOMIC_RELAXED, __HIP_MEMORY_SCOPE_AGENT);
}
__device__ __forceinline__ void cstore(float* p, float v) {
  __hip_atomic_store(p, v, __ATOMIC_RELAXED, __HIP_MEMORY_SCOPE_AGENT);
}
__device__ __forceinline__ void cstoreu(unsigned* p, unsigned v) {
  __hip_atomic_store(p, v, __ATOMIC_RELAXED, __HIP_MEMORY_SCOPE_AGENT);
}
__device__ __forceinline__ u64 cload64(const u64* p) {
  return __hip_atomic_load(p, __ATOMIC_RELAXED, __HIP_MEMORY_SCOPE_AGENT);
}
__device__ __forceinline__ float sigm(float x) {
  return __builtin_amdgcn_rcpf(1.f + __expf(-x));
}
__device__ __forceinline__ float tanh2(float x) {
  return 1.f - 2.f * __builtin_amdgcn_rcpf(1.f + __expf(x + x));
}
__device__ __forceinline__ f4v mfma16(s8v a, s8v b, f4v c) {
  return __builtin_amdgcn_mfma_f32_16x16x32_bf16(a, b, c, 0, 0, 0);
}

// 112-block store-slot barrier: posted arrivals; root polls all slots
// (batched loads), posts 8 per-XCD release flags.
__device__ __forceinline__ void gbar(unsigned* bar, int bid, unsigned& gen) {
  asm volatile("s_waitcnt vmcnt(0) lgkmcnt(0)" ::: "memory");
  __syncthreads();
  if (threadIdx.x == 0) {
    __atomic_signal_fence(__ATOMIC_SEQ_CST);
    gen++;
    __hip_atomic_store(bar + bid, gen, __ATOMIC_RELAXED, __HIP_MEMORY_SCOPE_AGENT);
    if (bid == 0) {
      for (;;) {
        unsigned mn = 0xffffffffu;
#pragma unroll
        for (int i = 0; i < 112; ++i) {
          unsigned v = __hip_atomic_load(bar + i, __ATOMIC_RELAXED,
                                         __HIP_MEMORY_SCOPE_AGENT);
          mn = (v < mn) ? v : mn;
        }
        if (mn >= gen) break;
        __builtin_amdgcn_s_sleep(0);
      }
#pragma unroll
      for (int l = 0; l < 8; ++l)
        __hip_atomic_store(bar + 128 + l * 16, gen, __ATOMIC_RELAXED,
                           __HIP_MEMORY_SCOPE_AGENT);
    } else {
      while (__hip_atomic_load(bar + 128 + (bid & 7) * 16, __ATOMIC_RELAXED,
                               __HIP_MEMORY_SCOPE_AGENT) < gen)
        __builtin_amdgcn_s_sleep(1);
    }
    __atomic_signal_fence(__ATOMIC_SEQ_CST);
  }
  __syncthreads();
}

// ---------------------------------------------------------------------------
// prep: wcat=[Wa|Whh|Wout] bf16, wih bf16, enc8 fp8
// ---------------------------------------------------------------------------
__global__ void __launch_bounds__(256) prep_kernel(
    const float* __restrict__ Wa, const float* __restrict__ Whh,
    const float* __restrict__ Wout, const float* __restrict__ Wih,
    const float* __restrict__ enc,
    unsigned short* __restrict__ wcat, unsigned short* __restrict__ wihb,
    unsigned char* __restrict__ enc8) {
  const size_t gid = (size_t)blockIdx.x * 256 + threadIdx.x;
  const size_t stride = (size_t)gridDim.x * 256;
  for (size_t i = gid; i < 2097152u; i += stride) {
    float v; unsigned short* d;
    if (i < 262144u)       { v = Wa[i];              d = wcat + i; }
    else if (i < 1048576u) { v = Whh[i - 262144u];   d = wcat + i; }
    else if (i < 1310720u) { v = Wout[i - 1048576u]; d = wcat + i; }
    else                   { v = Wih[i - 1310720u];  d = wihb + (i - 1310720u); }
    *d = f2bf(v);
  }
  for (size_t j = gid; j < 4194304u; j += stride) {
    float2 e = ((const float2*)enc)[j];
    int pk = __builtin_amdgcn_cvt_pk_fp8_f32(e.x, e.y, 0, false);
    ((unsigned short*)enc8)[j] = (unsigned short)(pk & 0xffff);
  }
}

// ---------------------------------------------------------------------------
// keys[b*256+s][h] = exp(2*(enc[b,s]·Ua[h] + bu[h]))  (bf16)
// ---------------------------------------------------------------------------
__global__ void __launch_bounds__(256) keys_kernel(
    const float* __restrict__ enc, const float* __restrict__ Ua,
    const float* __restrict__ bu, unsigned short* __restrict__ keysb) {
  const int tid = threadIdx.x;
  const int w = tid >> 6, lane = tid & 63, ln = lane & 15, kq = lane >> 4;
  const int mb = blockIdx.x >> 3, nb = blockIdx.x & 7;
  const int mrow = mb * 64 + w * 16 + ln;
  f4v acc[4] = {{0,0,0,0},{0,0,0,0},{0,0,0,0},{0,0,0,0}};
  for (int ks = 0; ks < 16; ++ks) {
    const float* ap = enc + (size_t)mrow * 512 + ks * 32 + kq * 8;
    s8v af;
#pragma unroll
    for (int j = 0; j < 8; ++j) af[j] = (short)f2bf(ap[j]);
#pragma unroll
    for (int nt = 0; nt < 4; ++nt) {
      int n = nb * 64 + nt * 16 + ln;
      const float* up = Ua + (size_t)n * 512 + ks * 32 + kq * 8;
      s8v bf;
#pragma unroll
      for (int j = 0; j < 8; ++j) bf[j] = (short)f2bf(up[j]);
      acc[nt] = mfma16(af, bf, acc[nt]);
    }
  }
#pragma unroll
  for (int nt = 0; nt < 4; ++nt) {
    int n = nb * 64 + nt * 16 + ln;
    float bias = bu[n];
#pragma unroll
    for (int r = 0; r < 4; ++r) {
      int gm = mb * 64 + w * 16 + kq * 4 + r;
      keysb[(size_t)gm * 512 + n] = f2bf(__expf(2.f * (acc[nt][r] + bias)));
    }
  }
}

// ---------------------------------------------------------------------------
// persistent decoder: 112 blocks x 512 threads.  x=bid&7 (XCD), q2=bid>>3.
//   q2<8  : B-block (attention), batch = x*8+q2
//   q2 8..11 : C-block, h-cols [x*64+(q2-8)*16 .. +16)
//   q2 12..13: L-block, logits cols [x*64 .. +64) (2 blocks)
// ---------------------------------------------------------------------------
__global__ void __launch_bounds__(512, 1) decoder_kernel(
    const float* __restrict__ ba_, const float* __restrict__ va_,
    const float* __restrict__ bih_, const float* __restrict__ bhh_,
    const float* __restrict__ bout_,
    const unsigned short* __restrict__ wcat, const unsigned short* __restrict__ wihb,
    const unsigned short* __restrict__ keysb, const unsigned char* __restrict__ enc8,
    unsigned* __restrict__ bar, unsigned short* __restrict__ hbf,
    unsigned short* __restrict__ ctxg, float* __restrict__ out) {
  const int bid = blockIdx.x, tid = threadIdx.x;
  const int w = tid >> 6, lane = tid & 63, ln = lane & 15, kq = lane >> 4;
  const int x = bid & 7, q2 = bid >> 3;

  float* logits = out;
  float* hfin   = out + OUT_HFIN;
  float* attn   = out + OUT_ATTN;

  __shared__ u64 hrowL[128];                 // B: own h row (bf16)
  __shared__ float EqL[512];                 // B: exp(2(q+ba))
  __shared__ float swL[256];
  __shared__ float cpart[2][256][2];
  __shared__ float gateX[6][64][17];         // C: gate exchange
  __shared__ float hL[64][16];               // C: persistent f32 h slice

  unsigned gen = 0;

  const bool isB = (q2 < 8);
  const int  bA  = x * 8 + q2;               // B batch
  const bool isC = (q2 >= 8 && q2 < 12);
  const bool isL = (q2 >= 12 && q2 < 14);
  const int  cb  = isC ? (x * 64 + (q2 - 8) * 16) : 0;   // C col base

  // ---- loop invariants ---------------------------------------------------
  float vav[8]; float vasum;
  {
    float vs = 0.f;
#pragma unroll
    for (int jj = 0; jj < 8; ++jj) { vav[jj] = va_[lane * 8 + jj]; vs += vav[jj]; }
#pragma unroll
    for (int off = 32; off > 0; off >>= 1) vs += __shfl_xor(vs, off, 64);
    vasum = vs;
  }
  // C: GRU biases for this thread's (b, col-pair)
  float bi_[6], bh_[6];
  {
    const int cp = tid & 7;
    const int c0 = cb + cp * 2;
#pragma unroll
    for (int g = 0; g < 3; ++g) {
      bi_[g * 2]     = bih_[g * 512 + c0];
      bi_[g * 2 + 1] = bih_[g * 512 + c0 + 1];
      bh_[g * 2]     = bhh_[g * 512 + c0];
      bh_[g * 2 + 1] = bhh_[g * 512 + c0 + 1];
    }
  }
  if (isC) { for (int i = tid; i < 1024; i += 512) ((float*)hL)[i] = 0.f; }
  __syncthreads();

#pragma clang loop unroll(disable)
  for (int it = 0; it <= 256; ++it) {
    const unsigned short* hbr = hbf + ((it + 1) & 1) * 32768;  // h(t-1)
    unsigned short* hbw       = hbf + (it & 1) * 32768;        // h(t)

    // ============ Phase 1: attention (B-blocks), computes q in-phase =======
    if (isB && it < 256) {
      if (tid < 128)
        hrowL[tid] = cload64((const u64*)(hbr + (size_t)bA * 512) + tid);
      __syncthreads();
      float hv[8];
      {
        union { u64 u[2]; unsigned short s[8]; } hu;
        hu.u[0] = hrowL[lane * 2]; hu.u[1] = hrowL[lane * 2 + 1];
#pragma unroll
        for (int j = 0; j < 8; ++j) hv[j] = bf2f(hu.s[j]);
      }
      // q-dot: wave w owns cols [w*64, w*64+64)
#pragma clang loop unroll_count(2)
      for (int i = 0; i < 64; ++i) {
        int col = w * 64 + i;
        s8v wa = *(const s8v*)(wcat + (size_t)col * 512 + lane * 8);
        float s = 0.f;
#pragma unroll
        for (int j = 0; j < 8; ++j) s += hv[j] * bf2f((unsigned short)wa[j]);
#pragma unroll
        for (int off = 32; off > 0; off >>= 1) s += __shfl_xor(s, off, 64);
        if (lane == 0) EqL[col] = __expf(2.f * (s + ba_[col]));
      }
      __syncthreads();
      // scores: wave w handles s in [w*32, w*32+32)
      {
        float eq[8];
#pragma unroll
        for (int jj = 0; jj < 8; ++jj) eq[jj] = EqL[lane * 8 + jj];
        const unsigned short* kbase =
            keysb + ((size_t)bA * 256 + w * 32) * 512 + lane * 8;
#pragma clang loop unroll(disable)
        for (int i0 = 0; i0 < 32; i0 += 8) {
          s8v kv[8];
#pragma unroll
          for (int i = 0; i < 8; ++i)
            kv[i] = *(const s8v*)(kbase + (size_t)(i0 + i) * 512);
#pragma unroll
          for (int i = 0; i < 8; ++i) {
            float a2 = 0.f;
#pragma unroll
            for (int jj = 0; jj < 8; ++jj) {
              float P = eq[jj] * bf2f((unsigned short)kv[i][jj]);
              a2 += vav[jj] * __builtin_amdgcn_rcpf(1.f + P);
            }
#pragma unroll
            for (int off = 32; off > 0; off >>= 1) a2 += __shfl_xor(a2, off, 64);
            if (lane == 0) swL[w * 32 + i0 + i] = __expf(vasum - 2.f * a2);
          }
        }
      }
      __syncthreads();
      // Z (all waves redundantly) + ctx partials over 2 halves of s
      float Z = 0.f;
      {
        float z4 = swL[lane] + swL[64 + lane] + swL[128 + lane] + swL[192 + lane];
#pragma unroll
        for (int off = 32; off > 0; off >>= 1) z4 += __shfl_xor(z4, off, 64);
        Z = z4;
      }
      float invZ = __builtin_amdgcn_rcpf(Z);
      {
        const int hp = tid & 255, sh = tid >> 8;
        const int s0 = sh * 128;
        const unsigned char* ep = enc8 + ((size_t)bA * 256 + s0) * 512 + hp * 2;
        float c0 = 0.f, c1 = 0.f;
#pragma unroll 8
        for (int i = 0; i < 128; ++i) {
          float wt = swL[s0 + i];
          unsigned short v8 = *(const unsigned short*)(ep + (size_t)i * 512);
          f2v ef = __builtin_amdgcn_cvt_pk_f32_fp8((int)v8, false);
          c0 += wt * ef[0]; c1 += wt * ef[1];
        }
        cpart[sh][hp][0] = c0; cpart[sh][hp][1] = c1;
      }
      __syncthreads();
      if (tid < 256) {
        float cc0 = (cpart[0][tid][0] + cpart[1][tid][0]) * invZ;
        float cc1 = (cpart[0][tid][1] + cpart[1][tid][1]) * invZ;
        unsigned pk = (unsigned)f2bf(cc0) | ((unsigned)f2bf(cc1) << 16);
        cstoreu((unsigned*)ctxg + (size_t)bA * 256 + tid, pk);
        attn[(size_t)bA * 65536 + (size_t)it * 256 + tid] = swL[tid] * invZ;
      }
    }
    gbar(bar, bid, gen);

    // ============ Phase 2: C (gh+gi+GRU) and L (logits) ====================
    if (isC && it < 256) {
      const int mt = w & 3, role = w >> 2;
      const int arow = mt * 16 + ln;
      // batched A-frag loads: ctx rows + h rows (32+32 cload64)
      u64 tc[32], th[32];
      {
        const u64* cx = (const u64*)(ctxg + (size_t)arow * 512);
        const u64* hx = (const u64*)(hbr + (size_t)arow * 512);
#pragma unroll
        for (int ks = 0; ks < 16; ++ks) {
          tc[2 * ks]     = cload64(cx + ks * 8 + kq * 2);
          tc[2 * ks + 1] = cload64(cx + ks * 8 + kq * 2 + 1);
        }
#pragma unroll
        for (int ks = 0; ks < 16; ++ks) {
          th[2 * ks]     = cload64(hx + ks * 8 + kq * 2);
          th[2 * ks + 1] = cload64(hx + ks * 8 + kq * 2 + 1);
        }
      }
      const int colC = cb + ln;
      const s8v* wir = (const s8v*)(wihb + (size_t)colC * 512);
      const s8v* wiz = (const s8v*)(wihb + (size_t)(512 + colC) * 512);
      const s8v* win = (const s8v*)(wihb + (size_t)(1024 + colC) * 512);
      const s8v* whr = (const s8v*)(wcat + (size_t)(512 + colC) * 512);
      const s8v* whz = (const s8v*)(wcat + (size_t)(1024 + colC) * 512);
      const s8v* whn = (const s8v*)(wcat + (size_t)(1536 + colC) * 512);
      f4v A0 = {0,0,0,0}, A1 = {0,0,0,0}, A2 = {0,0,0,0};
      if (role == 0) {          // aR, aZ (A=ctx); ghN (A=h)
#pragma unroll
        for (int ks = 0; ks < 16; ++ks) {
          union { u64 u[2]; s8v v; } au;
          au.u[0] = tc[2 * ks]; au.u[1] = tc[2 * ks + 1];
          A0 = mfma16(au.v, wir[ks * 4 + kq], A0);
          A1 = mfma16(au.v, wiz[ks * 4 + kq], A1);
        }
#pragma unroll
        for (int ks = 0; ks < 16; ++ks) {
          union { u64 u[2]; s8v v; } au;
          au.u[0] = th[2 * ks]; au.u[1] = th[2 * ks + 1];
          A2 = mfma16(au.v, whn[ks * 4 + kq], A2);
        }
      } else {                  // aN (A=ctx); ghR, ghZ (A=h)
#pragma unroll
        for (int ks = 0; ks < 16; ++ks) {
          union { u64 u[2]; s8v v; } au;
          au.u[0] = tc[2 * ks]; au.u[1] = tc[2 * ks + 1];
          A0 = mfma16(au.v, win[ks * 4 + kq], A0);
        }
#pragma unroll
        for (int ks = 0; ks < 16; ++ks) {
          union { u64 u[2]; s8v v; } au;
          au.u[0] = th[2 * ks]; au.u[1] = th[2 * ks + 1];
          A1 = mfma16(au.v, whr[ks * 4 + kq], A1);
          A2 = mfma16(au.v, whz[ks * 4 + kq], A2);
        }
      }
      {
        const int b0 = mt * 16 + kq * 4;
        const int c0 = (role == 0) ? 0 : 2;
        const int c1 = (role == 0) ? 1 : 3;
        const int c2 = (role == 0) ? 5 : 4;
#pragma unroll
        for (int r = 0; r < 4; ++r) {
          gateX[c0][b0 + r][ln] = A0[r];
          gateX[c1][b0 + r][ln] = A1[r];
          gateX[c2][b0 + r][ln] = A2[r];
        }
      }
      __syncthreads();
      // GRU: thread -> (b = tid>>3, col pair cp = tid&7)
      {
        const int b = tid >> 3, cp = tid & 7;
        float hn2[2];
#pragma unroll
        for (int u = 0; u < 2; ++u) {
          int c = cp * 2 + u;
          float aR = gateX[0][b][c], aZ = gateX[1][b][c], aN = gateX[2][b][c];
          float gR = gateX[3][b][c] + bh_[u];
          float gZ = gateX[4][b][c] + bh_[2 + u];
          float gN = gateX[5][b][c] + bh_[4 + u];
          float rr = sigm(aR + bi_[u] + gR);
          float zz = sigm(aZ + bi_[2 + u] + gZ);
          float nn = tanh2(aN + bi_[4 + u] + rr * gN);
          float hn = (1.f - zz) * nn + zz * hL[b][cp * 2 + u];
          hL[b][cp * 2 + u] = hn;
          hn2[u] = hn;
        }
        unsigned pk = (unsigned)f2bf(hn2[0]) | ((unsigned)f2bf(hn2[1]) << 16);
        cstoreu((unsigned*)hbw + (size_t)b * 256 + (cb >> 1) + cp, pk);
        if (it == 255) {
          hfin[(size_t)b * 512 + cb + cp * 2]     = hn2[0];
          hfin[(size_t)b * 512 + cb + cp * 2 + 1] = hn2[1];
        }
      }
    } else if (isL && it >= 1) {
      const int task = (q2 - 12) * 8 + w;        // 0..15
      const int tt = task >> 2, mt2 = task & 3;
      const int col = x * 64 + tt * 16 + ln;
      const u64* hx = (const u64*)(hbr + (size_t)(mt2 * 16 + ln) * 512);
      u64 tl[32];
#pragma unroll
      for (int ks = 0; ks < 16; ++ks) {
        tl[2 * ks]     = cload64(hx + ks * 8 + kq * 2);
        tl[2 * ks + 1] = cload64(hx + ks * 8 + kq * 2 + 1);
      }
      const s8v* wo = (const s8v*)(wcat + (size_t)(2048 + col) * 512);
      f4v acc = {0.f, 0.f, 0.f, 0.f};
#pragma unroll
      for (int ks = 0; ks < 16; ++ks) {
        union { u64 u[2]; s8v v; } au;
        au.u[0] = tl[2 * ks]; au.u[1] = tl[2 * ks + 1];
        acc = mfma16(au.v, wo[ks * 4 + kq], acc);
      }
      float bias = bout_[col];
#pragma unroll
      for (int r = 0; r < 4; ++r) {
        int bb2 = mt2 * 16 + kq * 4 + r;
        cstore(logits + (size_t)(it - 1) * 32768 + (size_t)bb2 * 512 + col,
               acc[r] + bias);
      }
    }
    gbar(bar, bid, gen);
  }

  // -------- finale: log_softmax over logits rows (bias already added) ------
#pragma clang loop unroll(disable)
  for (int row = bid * 8 + w; row < 16384; row += 896) {
    const u64* xr64 = (const u64*)(logits + (size_t)row * 512) + lane * 4;
    u64 t4[4];
#pragma unroll
    for (int jj = 0; jj < 4; ++jj) t4[jj] = cload64(xr64 + jj);
    union { u64 u[4]; float f[8]; } xu;
#pragma unroll
    for (int jj = 0; jj < 4; ++jj) xu.u[jj] = t4[jj];
    float mx = xu.f[0];
#pragma unroll
    for (int jj = 1; jj < 8; ++jj) mx = fmaxf(mx, xu.f[jj]);
#pragma unroll
    for (int off = 32; off > 0; off >>= 1) mx = fmaxf(mx, __shfl_xor(mx, off, 64));
    float sm = 0.f;
#pragma unroll
    for (int jj = 0; jj < 8; ++jj) sm += __expf(xu.f[jj] - mx);
#pragma unroll
    for (int off = 32; off > 0; off >>= 1) sm += __shfl_xor(sm, off, 64);
    float lse = mx + __logf(sm);
    float* xw = logits + (size_t)row * 512 + lane * 8;
    f4v o0, o1;
#pragma unroll
    for (int jj = 0; jj < 4; ++jj) { o0[jj] = xu.f[jj] - lse; o1[jj] = xu.f[4 + jj] - lse; }
    ((f4v*)xw)[0] = o0;
    ((f4v*)xw)[1] = o1;
  }
}

// ---------------------------------------------------------------------------
extern "C" void kernel_launch(void* const* d_in, const int* in_sizes, int n_in,
                              void* d_out, int out_size, void* d_ws, size_t ws_size,
                              hipStream_t stream) {
  const float* enc  = (const float*)d_in[0];
  const float* Wa   = (const float*)d_in[1];
  const float* ba   = (const float*)d_in[2];
  const float* Ua   = (const float*)d_in[3];
  const float* bu   = (const float*)d_in[4];
  const float* Va   = (const float*)d_in[5];
  // d_in[6] = bv : softmax-invariant, unused
  const float* Wih  = (const float*)d_in[7];
  const float* bih  = (const float*)d_in[8];
  const float* Whh  = (const float*)d_in[9];
  const float* bhh  = (const float*)d_in[10];
  const float* Wout = (const float*)d_in[11];
  const float* bout = (const float*)d_in[12];
  (void)in_sizes; (void)n_in; (void)out_size; (void)ws_size;

  char* ws = (char*)d_ws;
  unsigned*       bar   = (unsigned*)(ws + OFF_BAR);
  unsigned short* hbf   = (unsigned short*)(ws + OFF_HBF);
  unsigned short* ctxg  = (unsigned short*)(ws + OFF_CTX);
  unsigned short* wcat  = (unsigned short*)(ws + OFF_WCAT);
  unsigned short* wihb  = (unsigned short*)(ws + OFF_WIH);
  unsigned short* keysb = (unsigned short*)(ws + OFF_KEYS);
  unsigned char*  enc8  = (unsigned char*)(ws + OFF_ENC8);

  hipMemsetAsync(d_ws, 0, MEMSET_BYTES, stream);       // bar + h0 = 0 (both bufs)
  prep_kernel<<<1024, 256, 0, stream>>>(Wa, Whh, Wout, Wih, enc,
                                        wcat, wihb, enc8);
  keys_kernel<<<2048, 256, 0, stream>>>(enc, Ua, bu, keysb);
  decoder_kernel<<<112, 512, 0, stream>>>(ba, Va, bih, bhh, bout,
                                          wcat, wihb, keysb, enc8,
                                          bar, hbf, ctxg, (float*)d_out);
}